// Round 12
// baseline (398.236 us; speedup 1.0000x reference)
//
#include <hip/hip_runtime.h>
#include <climits>

// Voxel hash: 2^22 u64 slots (key<<32 | min_point_id), ~1.98M voxels, load 0.47.
// (Round-9 proven config. Round-11's 4B tag table was provably wrong: linear
// probing displaces entries, so (slot,tag) no longer identifies the key.)
#define HCAP (1 << 22)
typedef unsigned long long u64;
typedef float f32x4 __attribute__((ext_vector_type(4)));
typedef float f32x2 __attribute__((ext_vector_type(2)));
#define EMPTY64 0xFFFFFFFFFFFFFFFFULL

__device__ __forceinline__ unsigned fmix32(unsigned h) {
    h ^= h >> 16; h *= 0x85ebca6bu;
    h ^= h >> 13; h *= 0xc2b2ae35u;
    h ^= h >> 16;
    return h;
}

// Gold quant (verified round 7): XLA rewrites /0.02 -> *(1/0.02f); f32(1/0.02f)
// == 50.0f exactly. One f32 RN multiply + floor.
__device__ __forceinline__ int quant(float c) {
    return (int)floorf(c * 50.0f);
}

// K0: init packed table to EMPTY (16B vector stores)
__global__ void k_init(u64* __restrict__ tab) {
    int i = blockIdx.x * blockDim.x + threadIdx.x;
    if (i < HCAP / 2) {
        ulonglong2 v; v.x = EMPTY64; v.y = EMPTY64;
        ((ulonglong2*)tab)[i] = v;
    }
}

// K1 (round-9 verbatim): read-then-CAS claim/min on packed u64 slots.
__global__ void k_build(const float* __restrict__ coord,
                        u64* __restrict__ tab, int* __restrict__ slotp, int n) {
    int i = blockIdx.x * blockDim.x + threadIdx.x;
    if (i >= n) return;
    int g0 = quant(coord[i * 3 + 0]);
    int g1 = quant(coord[i * 3 + 1]);
    int g2 = quant(coord[i * 3 + 2]);
    unsigned key = ((unsigned)(g0 & 1023) << 20) | ((unsigned)(g1 & 1023) << 10)
                 | (unsigned)(g2 & 1023);
    u64 packed = ((u64)key << 32) | (unsigned)i;

    unsigned h = fmix32(key) & (HCAP - 1);
    int slot = -1;
    while (slot < 0) {
        u64 cur = tab[h];
        if (cur == EMPTY64) {
            u64 old = atomicCAS(&tab[h], EMPTY64, packed);
            if (old == EMPTY64) { slot = (int)h; break; }
            cur = old;
        }
        if ((unsigned)(cur >> 32) == key) {
            while ((unsigned)cur > (unsigned)i) {   // current min id > ours
                u64 old = atomicCAS(&tab[h], cur, packed);
                if (old == cur) break;
                cur = old;                          // key is stable post-claim
            }
            slot = (int)h;
            break;
        }
        h = (h + 1) & (HCAP - 1);
    }
    slotp[i] = slot;
}

// K2 (round-9 verbatim): per 256-point block: resolve rep, stage 9
// inputs/point in LDS, 18 coalesced nt float4 stores per point.
// MEASUREMENT ROUND: launched TWICE (idempotent — identical stores), so
// T_out = dur(this round) - dur(round 9).
__global__ void k_out(const float* __restrict__ feat, const float* __restrict__ coord,
                      const float* __restrict__ W, const float* __restrict__ Wc,
                      const int* __restrict__ slotp, const u64* __restrict__ tab,
                      float* __restrict__ out, int n) {
    __shared__ __align__(16) float wl[9 * 72];   // rows 0-5: W, rows 6-8: Wc
    __shared__ float pv[256 * 9];
    int t = threadIdx.x;
    for (int i = t; i < 648; i += 256) wl[i] = (i < 432) ? W[i] : Wc[i - 432];
    int base = blockIdx.x * 256;
    int p = base + t;
    if (p < n) {
        int r = (int)(unsigned)(tab[slotp[p]] & 0xFFFFFFFFu);  // min point id
        const f32x2* fr2 = (const f32x2*)(feat + (size_t)r * 6);  // 8B aligned
        const float* cr = coord + (size_t)r * 3;
        f32x2 a = fr2[0], b = fr2[1], c = fr2[2];
        pv[t * 9 + 0] = a.x; pv[t * 9 + 1] = a.y;
        pv[t * 9 + 2] = b.x; pv[t * 9 + 3] = b.y;
        pv[t * 9 + 4] = c.x; pv[t * 9 + 5] = c.y;
        pv[t * 9 + 6] = cr[0]; pv[t * 9 + 7] = cr[1]; pv[t * 9 + 8] = cr[2];
    }
    __syncthreads();
    f32x4* out4 = (f32x4*)out;
    #pragma unroll
    for (int j = 0; j < 18; ++j) {
        int flat = j * 256 + t;              // [0, 4608) = 256 points x 18 groups
        int pl = flat / 18, c4 = flat - pl * 18;
        int pp = base + pl;
        if (pp < n) {
            const float* vals = &pv[pl * 9];
            f32x4 acc = (f32x4)(0.f);
            #pragma unroll
            for (int q = 0; q < 9; ++q) {
                float v = vals[q];
                f32x4 wv = *(const f32x4*)&wl[q * 72 + c4 * 4];
                acc.x = fmaf(v, wv.x, acc.x);
                acc.y = fmaf(v, wv.y, acc.y);
                acc.z = fmaf(v, wv.z, acc.z);
                acc.w = fmaf(v, wv.w, acc.w);
            }
            __builtin_nontemporal_store(acc, &out4[(size_t)pp * 18 + c4]);
        }
    }
}

extern "C" void kernel_launch(void* const* d_in, const int* in_sizes, int n_in,
                              void* d_out, int out_size, void* d_ws, size_t ws_size,
                              hipStream_t stream) {
    const float* coord = (const float*)d_in[0];
    const float* feat  = (const float*)d_in[1];
    const float* W     = (const float*)d_in[2];
    const float* Wc    = (const float*)d_in[3];
    float* out = (float*)d_out;
    int n = in_sizes[0] / 3;

    // ws_size = 2.3 GB; we use 40 MB.
    u64* tab   = (u64*)d_ws;
    int* slotp = (int*)(tab + HCAP);

    k_init<<<(HCAP / 2 + 255) / 256, 256, 0, stream>>>(tab);
    k_build<<<(n + 255) / 256, 256, 0, stream>>>(coord, tab, slotp, n);
    k_out<<<(n + 255) / 256, 256, 0, stream>>>(feat, coord, W, Wc, slotp, tab, out, n);
    // Idempotent duplicate for timing decomposition (T_out = dur - 261us).
    k_out<<<(n + 255) / 256, 256, 0, stream>>>(feat, coord, W, Wc, slotp, tab, out, n);
}

// Round 13
// 280.370 us; speedup vs baseline: 1.4204x; 1.4204x over previous
//
#include <hip/hip_runtime.h>
#include <climits>

// Voxel hash: 2^22 u64 slots (key<<32 | min_point_id), ~1.98M voxels, load 0.47.
#define HCAP (1 << 22)
typedef unsigned long long u64;
typedef float f32x4 __attribute__((ext_vector_type(4)));
typedef float f32x2 __attribute__((ext_vector_type(2)));
#define EMPTY64 0xFFFFFFFFFFFFFFFFULL

__device__ __forceinline__ unsigned fmix32(unsigned h) {
    h ^= h >> 16; h *= 0x85ebca6bu;
    h ^= h >> 13; h *= 0xc2b2ae35u;
    h ^= h >> 16;
    return h;
}

// Gold quant (verified round 7): XLA rewrites /0.02 -> *(1/0.02f); f32(1/0.02f)
// == 50.0f exactly. One f32 RN multiply + floor.
__device__ __forceinline__ int quant(float c) {
    return (int)floorf(c * 50.0f);
}

// K0: init packed table to EMPTY (16B vector stores)
__global__ void k_init(u64* __restrict__ tab) {
    int i = blockIdx.x * blockDim.x + threadIdx.x;
    if (i < HCAP / 2) {
        ulonglong2 v; v.x = EMPTY64; v.y = EMPTY64;
        ((ulonglong2*)tab)[i] = v;
    }
}

// K1: CAS-FIRST claim/min (single-variable change vs round 9's read-then-CAS).
// A failed claim-CAS returns the occupant — it IS the read. 1 memory op per
// probe step vs ~2.5/point before. Ids per slot strictly decrease, key stable
// post-claim -> no livelock, identical final state.
__global__ void k_build(const float* __restrict__ coord,
                        u64* __restrict__ tab, int* __restrict__ slotp, int n) {
    int i = blockIdx.x * blockDim.x + threadIdx.x;
    if (i >= n) return;
    int g0 = quant(coord[i * 3 + 0]);
    int g1 = quant(coord[i * 3 + 1]);
    int g2 = quant(coord[i * 3 + 2]);
    unsigned key = ((unsigned)(g0 & 1023) << 20) | ((unsigned)(g1 & 1023) << 10)
                 | (unsigned)(g2 & 1023);
    u64 packed = ((u64)key << 32) | (unsigned)i;

    unsigned h = fmix32(key) & (HCAP - 1);
    for (;;) {
        u64 old = atomicCAS(&tab[h], EMPTY64, packed);
        if (old == EMPTY64) break;                    // claimed fresh slot
        if ((unsigned)(old >> 32) == key) {           // our voxel's slot
            u64 cur = old;
            while ((unsigned)cur > (unsigned)i) {     // current min id > ours
                u64 prev = atomicCAS(&tab[h], cur, packed);
                if (prev == cur) break;
                cur = prev;                           // key stable post-claim
            }
            break;
        }
        h = (h + 1) & (HCAP - 1);                     // foreign key: probe on
    }
    slotp[i] = (int)h;
}

// K2 (round-9 verbatim): per 256-point block: resolve rep, stage 9
// inputs/point in LDS, 18 coalesced nt float4 stores per point.
__global__ void k_out(const float* __restrict__ feat, const float* __restrict__ coord,
                      const float* __restrict__ W, const float* __restrict__ Wc,
                      const int* __restrict__ slotp, const u64* __restrict__ tab,
                      float* __restrict__ out, int n) {
    __shared__ __align__(16) float wl[9 * 72];   // rows 0-5: W, rows 6-8: Wc
    __shared__ float pv[256 * 9];
    int t = threadIdx.x;
    for (int i = t; i < 648; i += 256) wl[i] = (i < 432) ? W[i] : Wc[i - 432];
    int base = blockIdx.x * 256;
    int p = base + t;
    if (p < n) {
        int r = (int)(unsigned)(tab[slotp[p]] & 0xFFFFFFFFu);  // min point id
        const f32x2* fr2 = (const f32x2*)(feat + (size_t)r * 6);  // 8B aligned
        const float* cr = coord + (size_t)r * 3;
        f32x2 a = fr2[0], b = fr2[1], c = fr2[2];
        pv[t * 9 + 0] = a.x; pv[t * 9 + 1] = a.y;
        pv[t * 9 + 2] = b.x; pv[t * 9 + 3] = b.y;
        pv[t * 9 + 4] = c.x; pv[t * 9 + 5] = c.y;
        pv[t * 9 + 6] = cr[0]; pv[t * 9 + 7] = cr[1]; pv[t * 9 + 8] = cr[2];
    }
    __syncthreads();
    f32x4* out4 = (f32x4*)out;
    #pragma unroll
    for (int j = 0; j < 18; ++j) {
        int flat = j * 256 + t;              // [0, 4608) = 256 points x 18 groups
        int pl = flat / 18, c4 = flat - pl * 18;
        int pp = base + pl;
        if (pp < n) {
            const float* vals = &pv[pl * 9];
            f32x4 acc = (f32x4)(0.f);
            #pragma unroll
            for (int q = 0; q < 9; ++q) {
                float v = vals[q];
                f32x4 wv = *(const f32x4*)&wl[q * 72 + c4 * 4];
                acc.x = fmaf(v, wv.x, acc.x);
                acc.y = fmaf(v, wv.y, acc.y);
                acc.z = fmaf(v, wv.z, acc.z);
                acc.w = fmaf(v, wv.w, acc.w);
            }
            __builtin_nontemporal_store(acc, &out4[(size_t)pp * 18 + c4]);
        }
    }
}

extern "C" void kernel_launch(void* const* d_in, const int* in_sizes, int n_in,
                              void* d_out, int out_size, void* d_ws, size_t ws_size,
                              hipStream_t stream) {
    const float* coord = (const float*)d_in[0];
    const float* feat  = (const float*)d_in[1];
    const float* W     = (const float*)d_in[2];
    const float* Wc    = (const float*)d_in[3];
    float* out = (float*)d_out;
    int n = in_sizes[0] / 3;

    // ws_size = 2.3 GB; we use 40 MB.
    u64* tab   = (u64*)d_ws;
    int* slotp = (int*)(tab + HCAP);

    k_init<<<(HCAP / 2 + 255) / 256, 256, 0, stream>>>(tab);
    k_build<<<(n + 255) / 256, 256, 0, stream>>>(coord, tab, slotp, n);
    k_out<<<(n + 255) / 256, 256, 0, stream>>>(feat, coord, W, Wc, slotp, tab, out, n);
}

// Round 14
// 255.540 us; speedup vs baseline: 1.5584x; 1.0972x over previous
//
#include <hip/hip_runtime.h>
#include <climits>

// Voxel hash: 2^23 u64 slots (64 MB), ~1.98M voxels -> load 0.236.
// (Round 14: single change vs round-9 champion = HCAP 2^22 -> 2^23.
//  Shorter probe chains: wave-max probe iterations ~4-5 -> ~2-3.)
#define HCAP (1 << 23)
typedef unsigned long long u64;
typedef float f32x4 __attribute__((ext_vector_type(4)));
typedef float f32x2 __attribute__((ext_vector_type(2)));
#define EMPTY64 0xFFFFFFFFFFFFFFFFULL

__device__ __forceinline__ unsigned fmix32(unsigned h) {
    h ^= h >> 16; h *= 0x85ebca6bu;
    h ^= h >> 13; h *= 0xc2b2ae35u;
    h ^= h >> 16;
    return h;
}

// Gold quant (verified round 7): XLA rewrites /0.02 -> *(1/0.02f); f32(1/0.02f)
// == 50.0f exactly. One f32 RN multiply + floor.
__device__ __forceinline__ int quant(float c) {
    return (int)floorf(c * 50.0f);
}

// K0: init packed table to EMPTY (16B vector stores)
__global__ void k_init(u64* __restrict__ tab) {
    int i = blockIdx.x * blockDim.x + threadIdx.x;
    if (i < HCAP / 2) {
        ulonglong2 v; v.x = EMPTY64; v.y = EMPTY64;
        ((ulonglong2*)tab)[i] = v;
    }
}

// K1 (round-9 protocol, proven fastest): read-then-CAS claim/min.
// Plain probe reads stay shared-state; CAS only on claim or min-improve.
// Ids per slot strictly decrease; key stable post-claim -> no livelock.
__global__ void k_build(const float* __restrict__ coord,
                        u64* __restrict__ tab, int* __restrict__ slotp, int n) {
    int i = blockIdx.x * blockDim.x + threadIdx.x;
    if (i >= n) return;
    int g0 = quant(coord[i * 3 + 0]);
    int g1 = quant(coord[i * 3 + 1]);
    int g2 = quant(coord[i * 3 + 2]);
    unsigned key = ((unsigned)(g0 & 1023) << 20) | ((unsigned)(g1 & 1023) << 10)
                 | (unsigned)(g2 & 1023);
    u64 packed = ((u64)key << 32) | (unsigned)i;

    unsigned h = fmix32(key) & (HCAP - 1);
    int slot = -1;
    while (slot < 0) {
        u64 cur = tab[h];
        if (cur == EMPTY64) {
            u64 old = atomicCAS(&tab[h], EMPTY64, packed);
            if (old == EMPTY64) { slot = (int)h; break; }
            cur = old;
        }
        if ((unsigned)(cur >> 32) == key) {
            while ((unsigned)cur > (unsigned)i) {   // current min id > ours
                u64 old = atomicCAS(&tab[h], cur, packed);
                if (old == cur) break;
                cur = old;                          // key is stable post-claim
            }
            slot = (int)h;
            break;
        }
        h = (h + 1) & (HCAP - 1);
    }
    slotp[i] = slot;
}

// K2 (round-9 verbatim): per 256-point block: resolve rep, stage 9
// inputs/point in LDS, 18 coalesced nt float4 stores per point.
__global__ void k_out(const float* __restrict__ feat, const float* __restrict__ coord,
                      const float* __restrict__ W, const float* __restrict__ Wc,
                      const int* __restrict__ slotp, const u64* __restrict__ tab,
                      float* __restrict__ out, int n) {
    __shared__ __align__(16) float wl[9 * 72];   // rows 0-5: W, rows 6-8: Wc
    __shared__ float pv[256 * 9];
    int t = threadIdx.x;
    for (int i = t; i < 648; i += 256) wl[i] = (i < 432) ? W[i] : Wc[i - 432];
    int base = blockIdx.x * 256;
    int p = base + t;
    if (p < n) {
        int r = (int)(unsigned)(tab[slotp[p]] & 0xFFFFFFFFu);  // min point id
        const f32x2* fr2 = (const f32x2*)(feat + (size_t)r * 6);  // 8B aligned
        const float* cr = coord + (size_t)r * 3;
        f32x2 a = fr2[0], b = fr2[1], c = fr2[2];
        pv[t * 9 + 0] = a.x; pv[t * 9 + 1] = a.y;
        pv[t * 9 + 2] = b.x; pv[t * 9 + 3] = b.y;
        pv[t * 9 + 4] = c.x; pv[t * 9 + 5] = c.y;
        pv[t * 9 + 6] = cr[0]; pv[t * 9 + 7] = cr[1]; pv[t * 9 + 8] = cr[2];
    }
    __syncthreads();
    f32x4* out4 = (f32x4*)out;
    #pragma unroll
    for (int j = 0; j < 18; ++j) {
        int flat = j * 256 + t;              // [0, 4608) = 256 points x 18 groups
        int pl = flat / 18, c4 = flat - pl * 18;
        int pp = base + pl;
        if (pp < n) {
            const float* vals = &pv[pl * 9];
            f32x4 acc = (f32x4)(0.f);
            #pragma unroll
            for (int q = 0; q < 9; ++q) {
                float v = vals[q];
                f32x4 wv = *(const f32x4*)&wl[q * 72 + c4 * 4];
                acc.x = fmaf(v, wv.x, acc.x);
                acc.y = fmaf(v, wv.y, acc.y);
                acc.z = fmaf(v, wv.z, acc.z);
                acc.w = fmaf(v, wv.w, acc.w);
            }
            __builtin_nontemporal_store(acc, &out4[(size_t)pp * 18 + c4]);
        }
    }
}

extern "C" void kernel_launch(void* const* d_in, const int* in_sizes, int n_in,
                              void* d_out, int out_size, void* d_ws, size_t ws_size,
                              hipStream_t stream) {
    const float* coord = (const float*)d_in[0];
    const float* feat  = (const float*)d_in[1];
    const float* W     = (const float*)d_in[2];
    const float* Wc    = (const float*)d_in[3];
    float* out = (float*)d_out;
    int n = in_sizes[0] / 3;

    // ws_size = 2.3 GB; we use 72 MB.
    u64* tab   = (u64*)d_ws;
    int* slotp = (int*)(tab + HCAP);

    k_init<<<(HCAP / 2 + 255) / 256, 256, 0, stream>>>(tab);
    k_build<<<(n + 255) / 256, 256, 0, stream>>>(coord, tab, slotp, n);
    k_out<<<(n + 255) / 256, 256, 0, stream>>>(feat, coord, W, Wc, slotp, tab, out, n);
}